// Round 2
// baseline (601.191 us; speedup 1.0000x reference)
//
#include <hip/hip_runtime.h>

typedef __attribute__((ext_vector_type(8))) short short8;
typedef __attribute__((ext_vector_type(4))) float f32x4;

#define NB 4
#define NN 512
#define ND 512
#define NH 16
#define NDH 32
#define NPAIR 64

static __device__ __forceinline__ unsigned short f2bf(float f) {
    union { float f; unsigned int i; } x; x.f = f;
    unsigned int i = x.i;
    unsigned int r = (i + 0x7fffu + ((i >> 16) & 1u)) >> 16;
    return (unsigned short)r;
}

static __device__ __forceinline__ short8 cvt8(const float4 lo, const float4 hi) {
    short8 r;
    r[0] = (short)f2bf(lo.x); r[1] = (short)f2bf(lo.y);
    r[2] = (short)f2bf(lo.z); r[3] = (short)f2bf(lo.w);
    r[4] = (short)f2bf(hi.x); r[5] = (short)f2bf(hi.y);
    r[6] = (short)f2bf(hi.z); r[7] = (short)f2bf(hi.w);
    return r;
}

// ---------------------------------------------------------------------------
// K1: QKV projection (fp32 VALU). x[2048,512] @ W[512,512].
// q,k -> fp32 [b,h,n,dh]; v -> bf16 transposed [b,h,dh,n] (for av MFMA).
// grid (256, 3), block 256; 8-row tiles; thread owns 2 adjacent cols.
// ---------------------------------------------------------------------------
__global__ __launch_bounds__(256) void qkv_kernel(
    const float* __restrict__ x, const float* __restrict__ Wq,
    const float* __restrict__ Wk, const float* __restrict__ Wv,
    float* __restrict__ q_ws, float* __restrict__ k_ws, ushort* __restrict__ vT_ws)
{
    __shared__ float xs[8 * 512];
    const int tid = threadIdx.x;
    const int row0 = blockIdx.x * 8;
    const int which = blockIdx.y;
    const float* W = (which == 0) ? Wq : (which == 1) ? Wk : Wv;

    {
        const float4* xg = (const float4*)(x + row0 * 512);
        float4* s = (float4*)xs;
        #pragma unroll
        for (int i = 0; i < 4; ++i) s[tid + i * 256] = xg[tid + i * 256];
    }
    __syncthreads();

    const int c0 = tid * 2;
    float acc[8][2];
    #pragma unroll
    for (int r = 0; r < 8; ++r) { acc[r][0] = 0.f; acc[r][1] = 0.f; }

    for (int kk = 0; kk < 512; kk += 4) {
        float w[4][2];
        #pragma unroll
        for (int j = 0; j < 4; ++j) {
            const float2 u = *(const float2*)(W + (kk + j) * 512 + c0);
            w[j][0] = u.x; w[j][1] = u.y;
        }
        #pragma unroll
        for (int r = 0; r < 8; ++r) {
            const float4 xv = *(const float4*)(xs + r * 512 + kk);
            acc[r][0] = fmaf(xv.x, w[0][0], acc[r][0]);
            acc[r][1] = fmaf(xv.x, w[0][1], acc[r][1]);
            acc[r][0] = fmaf(xv.y, w[1][0], acc[r][0]);
            acc[r][1] = fmaf(xv.y, w[1][1], acc[r][1]);
            acc[r][0] = fmaf(xv.z, w[2][0], acc[r][0]);
            acc[r][1] = fmaf(xv.z, w[2][1], acc[r][1]);
            acc[r][0] = fmaf(xv.w, w[3][0], acc[r][0]);
            acc[r][1] = fmaf(xv.w, w[3][1], acc[r][1]);
        }
    }

    const int h = c0 >> 5, dh = c0 & 31;
    #pragma unroll
    for (int r = 0; r < 8; ++r) {
        int row = row0 + r, b = row >> 9, n = row & 511;
        if (which < 2) {
            float* dst = (which == 0 ? q_ws : k_ws) + (((b * 16 + h) * 512 + n) * 32 + dh);
            *(float2*)dst = make_float2(acc[r][0], acc[r][1]);
        } else {
            ushort* base = vT_ws + ((b * 16 + h) * 32 + dh) * 512 + n;
            base[0]   = f2bf(acc[r][0]);
            base[512] = f2bf(acc[r][1]);
        }
    }
}

// ---------------------------------------------------------------------------
// K2: bias[b,h,n,m] = pair_bias[b,n,m,:] @ Wp[:,h]  via MFMA 16x16x32 bf16
// (fp32 inputs converted on load). Writes fp32 into the attn region of d_out.
// grid 2048 x 256; wave does 8 m-tiles of one (b,n) group.
// ---------------------------------------------------------------------------
__global__ __launch_bounds__(256) void bias_kernel(
    const float* __restrict__ pb, const float* __restrict__ Wp,
    float* __restrict__ bias_out)
{
    const int tid = threadIdx.x;
    const int lane = tid & 63, wid = tid >> 6;
    const int col = lane & 15, quad = lane >> 4;

    short8 b0, b1;
    #pragma unroll
    for (int j = 0; j < 8; ++j) {
        b0[j] = (short)f2bf(Wp[(quad * 8 + j) * 16 + col]);
        b1[j] = (short)f2bf(Wp[(32 + quad * 8 + j) * 16 + col]);
    }

    const int gw = blockIdx.x * 4 + wid;
    #pragma unroll
    for (int i = 0; i < 8; ++i) {
        int tile = gw * 8 + i;                    // tile = b*16384 + n*32 + mt
        int mt = tile & 31, n = (tile >> 5) & 511, b = tile >> 14;
        int m0 = mt * 16;
        const float* ap = pb + ((size_t)((b * 512 + n) * 512) + m0 + col) * 64 + quad * 8;
        short8 a0 = cvt8(*(const float4*)(ap),      *(const float4*)(ap + 4));
        short8 a1 = cvt8(*(const float4*)(ap + 32), *(const float4*)(ap + 36));
        f32x4 acc = {0.f, 0.f, 0.f, 0.f};
        acc = __builtin_amdgcn_mfma_f32_16x16x32_bf16(a0, b0, acc, 0, 0, 0);
        acc = __builtin_amdgcn_mfma_f32_16x16x32_bf16(a1, b1, acc, 0, 0, 0);
        // D: col = h, row = quad*4 + reg = m offset
        float4 o = make_float4(acc[0], acc[1], acc[2], acc[3]);
        *(float4*)(bias_out + ((size_t)(b * 16 + col) * 512 + n) * 512 + m0 + quad * 4) = o;
    }
}

// ---------------------------------------------------------------------------
// K3: scores + masks + softmax -> attn fp32 (in-place over bias region).
// grid 1024 = (b*h)*16 n-tiles of 32 rows; block 256; thread owns keys tid, tid+256.
// ---------------------------------------------------------------------------
__global__ __launch_bounds__(256) void attn_kernel(
    const float* __restrict__ q_ws, const float* __restrict__ k_ws,
    const int* __restrict__ am, float* __restrict__ attn)
{
    __shared__ float qs[32 * 32];
    __shared__ int amq[32];
    __shared__ float wred[8];
    const int tid = threadIdx.x, lane = tid & 63, wid = tid >> 6;
    const int bh = blockIdx.x >> 4, nt = blockIdx.x & 15;
    const int b = bh >> 4;
    const int n0 = nt * 32;

    {
        const float4* qg = (const float4*)(q_ws + (size_t)(bh * 512 + n0) * 32);
        ((float4*)qs)[tid] = qg[tid];          // 256 float4 = 32x32 fp32
    }
    if (tid < 32) amq[tid] = am[b * 512 + n0 + tid];

    float k0[32], k1[32];
    {
        const float4* kp  = (const float4*)(k_ws + (size_t)(bh * 512 + tid) * 32);
        const float4* kp2 = (const float4*)(k_ws + (size_t)(bh * 512 + tid + 256) * 32);
        #pragma unroll
        for (int j = 0; j < 8; ++j) {
            float4 u = kp[j];
            k0[j * 4 + 0] = u.x; k0[j * 4 + 1] = u.y; k0[j * 4 + 2] = u.z; k0[j * 4 + 3] = u.w;
            float4 u2 = kp2[j];
            k1[j * 4 + 0] = u2.x; k1[j * 4 + 1] = u2.y; k1[j * 4 + 2] = u2.z; k1[j * 4 + 3] = u2.w;
        }
    }
    const int km0 = am[b * 512 + tid];
    const int km1 = am[b * 512 + 256 + tid];
    __syncthreads();

    const float scale = 0.17677669529663687f;   // 1/sqrt(32)
    float* arow = attn + (size_t)(bh * 512 + n0) * 512;

    for (int r = 0; r < 32; ++r) {
        float s0 = 0.f, s1 = 0.f;
        const float4* q4 = (const float4*)(qs + r * 32);
        #pragma unroll
        for (int j = 0; j < 8; ++j) {
            float4 qv = q4[j];
            s0 = fmaf(qv.x, k0[j * 4 + 0], s0); s1 = fmaf(qv.x, k1[j * 4 + 0], s1);
            s0 = fmaf(qv.y, k0[j * 4 + 1], s0); s1 = fmaf(qv.y, k1[j * 4 + 1], s1);
            s0 = fmaf(qv.z, k0[j * 4 + 2], s0); s1 = fmaf(qv.z, k1[j * 4 + 2], s1);
            s0 = fmaf(qv.w, k0[j * 4 + 3], s0); s1 = fmaf(qv.w, k1[j * 4 + 3], s1);
        }
        float bias0 = arow[r * 512 + tid];
        float bias1 = arow[r * 512 + tid + 256];
        int rm = amq[r];
        s0 = s0 * scale + ((rm && km0) ? bias0 : 0.f);
        s1 = s1 * scale + ((rm && km1) ? bias1 : 0.f);
        if (!km0) s0 = -1e6f;
        if (!km1) s1 = -1e6f;

        float mloc = fmaxf(s0, s1);
        #pragma unroll
        for (int off = 32; off > 0; off >>= 1) mloc = fmaxf(mloc, __shfl_xor(mloc, off));
        if (lane == 0) wred[wid] = mloc;
        __syncthreads();
        float mx = fmaxf(fmaxf(wred[0], wred[1]), fmaxf(wred[2], wred[3]));
        float p0 = __expf(s0 - mx), p1 = __expf(s1 - mx);
        float sl = p0 + p1;
        #pragma unroll
        for (int off = 32; off > 0; off >>= 1) sl += __shfl_xor(sl, off);
        if (lane == 0) wred[4 + wid] = sl;
        __syncthreads();
        float inv = 1.0f / (wred[4] + wred[5] + wred[6] + wred[7]);
        arow[r * 512 + tid]       = p0 * inv;
        arow[r * 512 + tid + 256] = p1 * inv;
        __syncthreads();   // protect wred reuse next row
    }
}

// ---------------------------------------------------------------------------
// K4: out[b,n,h*32+dh] = attn[b,h,n,:] @ v  via MFMA (attn fp32 -> bf16 on
// load; v pre-transposed bf16). grid 512 x 256; wave-tile = 16 q-rows x 32 dh.
// ---------------------------------------------------------------------------
__global__ __launch_bounds__(256) void av_kernel(
    const float* __restrict__ attn, const ushort* __restrict__ vT,
    float* __restrict__ out_ws)
{
    const int tid = threadIdx.x, lane = tid & 63, wid = tid >> 6;
    const int col = lane & 15, quad = lane >> 4;
    const int wt = blockIdx.x * 4 + wid;     // 0..2047
    const int rt = wt & 31, bh = wt >> 5;
    const int n0 = rt * 16;

    const float*  ap  = attn + (size_t)(bh * 512 + n0 + col) * 512 + quad * 8;
    const ushort* vp0 = vT + (size_t)(bh * 32 + col) * 512 + quad * 8;
    const ushort* vp1 = vp0 + 16 * 512;

    f32x4 acc0 = {0.f, 0.f, 0.f, 0.f}, acc1 = {0.f, 0.f, 0.f, 0.f};
    #pragma unroll 4
    for (int kc = 0; kc < 16; ++kc) {
        int mo = kc * 32;
        short8 a  = cvt8(*(const float4*)(ap + mo), *(const float4*)(ap + mo + 4));
        short8 v0 = *(const short8*)(vp0 + mo);
        short8 v1 = *(const short8*)(vp1 + mo);
        acc0 = __builtin_amdgcn_mfma_f32_16x16x32_bf16(a, v0, acc0, 0, 0, 0);
        acc1 = __builtin_amdgcn_mfma_f32_16x16x32_bf16(a, v1, acc1, 0, 0, 0);
    }
    const int b = bh >> 4, h = bh & 15;
    float* op = out_ws + (size_t)(b * 512 + n0 + quad * 4) * 512 + h * 32;
    #pragma unroll
    for (int r = 0; r < 4; ++r) {
        op[r * 512 + col]      = acc0[r];
        op[r * 512 + 16 + col] = acc1[r];
    }
}

// ---------------------------------------------------------------------------
// K5: final = (out @ Wo) * row_mask -> fp32. grid 256 x 256; 8-row tiles.
// ---------------------------------------------------------------------------
__global__ __launch_bounds__(256) void out_kernel(
    const float* __restrict__ out_in, const float* __restrict__ Wo,
    const int* __restrict__ am, float* __restrict__ fin)
{
    __shared__ float xs[8 * 512];
    const int tid = threadIdx.x;
    const int row0 = blockIdx.x * 8;
    {
        const float4* g = (const float4*)(out_in + (size_t)row0 * 512);
        float4* s = (float4*)xs;
        #pragma unroll
        for (int i = 0; i < 4; ++i) s[tid + i * 256] = g[tid + i * 256];
    }
    __syncthreads();

    const int c0 = tid * 2;
    float acc[8][2];
    #pragma unroll
    for (int r = 0; r < 8; ++r) { acc[r][0] = 0.f; acc[r][1] = 0.f; }

    for (int kk = 0; kk < 512; kk += 4) {
        float w[4][2];
        #pragma unroll
        for (int j = 0; j < 4; ++j) {
            const float2 u = *(const float2*)(Wo + (kk + j) * 512 + c0);
            w[j][0] = u.x; w[j][1] = u.y;
        }
        #pragma unroll
        for (int r = 0; r < 8; ++r) {
            const float4 xv = *(const float4*)(xs + r * 512 + kk);
            acc[r][0] = fmaf(xv.x, w[0][0], acc[r][0]);
            acc[r][1] = fmaf(xv.x, w[0][1], acc[r][1]);
            acc[r][0] = fmaf(xv.y, w[1][0], acc[r][0]);
            acc[r][1] = fmaf(xv.y, w[1][1], acc[r][1]);
            acc[r][0] = fmaf(xv.z, w[2][0], acc[r][0]);
            acc[r][1] = fmaf(xv.z, w[2][1], acc[r][1]);
            acc[r][0] = fmaf(xv.w, w[3][0], acc[r][0]);
            acc[r][1] = fmaf(xv.w, w[3][1], acc[r][1]);
        }
    }
    #pragma unroll
    for (int r = 0; r < 8; ++r) {
        int row = row0 + r, b = row >> 9, n = row & 511;
        float msk = am[b * 512 + n] ? 1.0f : 0.0f;
        *(float2*)(fin + (size_t)row * 512 + c0) =
            make_float2(acc[r][0] * msk, acc[r][1] * msk);
    }
}

extern "C" void kernel_launch(void* const* d_in, const int* in_sizes, int n_in,
                              void* d_out, int out_size, void* d_ws, size_t ws_size,
                              hipStream_t stream)
{
    const float* x  = (const float*)d_in[0];
    const float* pb = (const float*)d_in[1];
    const float* Wq = (const float*)d_in[2];
    const float* Wk = (const float*)d_in[3];
    const float* Wv = (const float*)d_in[4];
    const float* Wo = (const float*)d_in[5];
    const float* Wp = (const float*)d_in[6];
    const int*   am = (const int*)d_in[7];

    float* fin  = (float*)d_out;
    float* attn = fin + (size_t)NB * NN * ND;      // 1,048,576 floats in

    float*  q_ws   = (float*)d_ws;                                  // 4 MB
    float*  k_ws   = (float*)((char*)d_ws + 4u * 1024 * 1024);      // 4 MB
    ushort* vT     = (ushort*)((char*)d_ws + 8u * 1024 * 1024);     // 2 MB
    float*  out_ws = (float*)((char*)d_ws + 10u * 1024 * 1024);     // 4 MB

    hipLaunchKernelGGL(qkv_kernel, dim3(256, 3), dim3(256), 0, stream,
                       x, Wq, Wk, Wv, q_ws, k_ws, vT);
    hipLaunchKernelGGL(bias_kernel, dim3(2048), dim3(256), 0, stream,
                       pb, Wp, attn);
    hipLaunchKernelGGL(attn_kernel, dim3(1024), dim3(256), 0, stream,
                       q_ws, k_ws, am, attn);
    hipLaunchKernelGGL(av_kernel, dim3(512), dim3(256), 0, stream,
                       attn, vT, out_ws);
    hipLaunchKernelGGL(out_kernel, dim3(256), dim3(256), 0, stream,
                       out_ws, Wo, am, fin);
}

// Round 3
// 594.898 us; speedup vs baseline: 1.0106x; 1.0106x over previous
//
#include <hip/hip_runtime.h>

typedef __attribute__((ext_vector_type(8))) short short8;
typedef __attribute__((ext_vector_type(4))) float f32x4;

#define NB 4
#define NN 512
#define ND 512
#define NH 16
#define NDH 32
#define NPAIR 64

static __device__ __forceinline__ float bf2f(unsigned short u) {
    union { unsigned int i; float f; } x; x.i = ((unsigned int)u) << 16; return x.f;
}
static __device__ __forceinline__ unsigned short f2bf(float f) {
    union { float f; unsigned int i; } x; x.f = f;
    unsigned int i = x.i;
    unsigned int r = (i + 0x7fffu + ((i >> 16) & 1u)) >> 16;
    return (unsigned short)r;
}
static __device__ __forceinline__ short8 cvt8(const float4 lo, const float4 hi) {
    short8 r;
    r[0] = (short)f2bf(lo.x); r[1] = (short)f2bf(lo.y);
    r[2] = (short)f2bf(lo.z); r[3] = (short)f2bf(lo.w);
    r[4] = (short)f2bf(hi.x); r[5] = (short)f2bf(hi.y);
    r[6] = (short)f2bf(hi.z); r[7] = (short)f2bf(hi.w);
    return r;
}

// ---------------------------------------------------------------------------
// K1: QKV projection (fp32 VALU). x[2048,512] @ W[512,512].
// q,k -> fp32 [b,h,n,dh]; v -> bf16 transposed [b,h,dh,n] (for av MFMA).
// grid (256, 3), block 256; 8-row tiles; thread owns 2 adjacent cols.
// ---------------------------------------------------------------------------
__global__ __launch_bounds__(256) void qkv_kernel(
    const float* __restrict__ x, const float* __restrict__ Wq,
    const float* __restrict__ Wk, const float* __restrict__ Wv,
    float* __restrict__ q_ws, float* __restrict__ k_ws, ushort* __restrict__ vT_ws)
{
    __shared__ float xs[8 * 512];
    const int tid = threadIdx.x;
    const int row0 = blockIdx.x * 8;
    const int which = blockIdx.y;
    const float* W = (which == 0) ? Wq : (which == 1) ? Wk : Wv;

    {
        const float4* xg = (const float4*)(x + row0 * 512);
        float4* s = (float4*)xs;
        #pragma unroll
        for (int i = 0; i < 4; ++i) s[tid + i * 256] = xg[tid + i * 256];
    }
    __syncthreads();

    const int c0 = tid * 2;
    float acc[8][2];
    #pragma unroll
    for (int r = 0; r < 8; ++r) { acc[r][0] = 0.f; acc[r][1] = 0.f; }

    for (int kk = 0; kk < 512; kk += 4) {
        float w[4][2];
        #pragma unroll
        for (int j = 0; j < 4; ++j) {
            const float2 u = *(const float2*)(W + (kk + j) * 512 + c0);
            w[j][0] = u.x; w[j][1] = u.y;
        }
        #pragma unroll
        for (int r = 0; r < 8; ++r) {
            const float4 xv = *(const float4*)(xs + r * 512 + kk);
            acc[r][0] = fmaf(xv.x, w[0][0], acc[r][0]);
            acc[r][1] = fmaf(xv.x, w[0][1], acc[r][1]);
            acc[r][0] = fmaf(xv.y, w[1][0], acc[r][0]);
            acc[r][1] = fmaf(xv.y, w[1][1], acc[r][1]);
            acc[r][0] = fmaf(xv.z, w[2][0], acc[r][0]);
            acc[r][1] = fmaf(xv.z, w[2][1], acc[r][1]);
            acc[r][0] = fmaf(xv.w, w[3][0], acc[r][0]);
            acc[r][1] = fmaf(xv.w, w[3][1], acc[r][1]);
        }
    }

    const int h = c0 >> 5, dh = c0 & 31;
    #pragma unroll
    for (int r = 0; r < 8; ++r) {
        int row = row0 + r, b = row >> 9, n = row & 511;
        if (which < 2) {
            float* dst = (which == 0 ? q_ws : k_ws) + (((b * 16 + h) * 512 + n) * 32 + dh);
            *(float2*)dst = make_float2(acc[r][0], acc[r][1]);
        } else {
            ushort* base = vT_ws + ((b * 16 + h) * 32 + dh) * 512 + n;
            base[0]   = f2bf(acc[r][0]);
            base[512] = f2bf(acc[r][1]);
        }
    }
}

// ---------------------------------------------------------------------------
// K2: bias[b,h,n,m] = pair_bias[b,n,m,:] @ Wp[:,h]  via MFMA 16x16x32 bf16.
// Output now bf16 into ws (halves the round-trip traffic vs fp32).
// grid 2048 x 256; wave does 8 m-tiles of one (b,n) group.
// ---------------------------------------------------------------------------
__global__ __launch_bounds__(256) void bias_kernel(
    const float* __restrict__ pb, const float* __restrict__ Wp,
    ushort* __restrict__ bias_ws)
{
    const int tid = threadIdx.x;
    const int lane = tid & 63, wid = tid >> 6;
    const int col = lane & 15, quad = lane >> 4;

    short8 b0, b1;
    #pragma unroll
    for (int j = 0; j < 8; ++j) {
        b0[j] = (short)f2bf(Wp[(quad * 8 + j) * 16 + col]);
        b1[j] = (short)f2bf(Wp[(32 + quad * 8 + j) * 16 + col]);
    }

    const int gw = blockIdx.x * 4 + wid;
    #pragma unroll
    for (int i = 0; i < 8; ++i) {
        int tile = gw * 8 + i;                    // tile = b*16384 + n*32 + mt
        int mt = tile & 31, n = (tile >> 5) & 511, b = tile >> 14;
        int m0 = mt * 16;
        const float* ap = pb + ((size_t)((b * 512 + n) * 512) + m0 + col) * 64 + quad * 8;
        short8 a0 = cvt8(*(const float4*)(ap),      *(const float4*)(ap + 4));
        short8 a1 = cvt8(*(const float4*)(ap + 32), *(const float4*)(ap + 36));
        f32x4 acc = {0.f, 0.f, 0.f, 0.f};
        acc = __builtin_amdgcn_mfma_f32_16x16x32_bf16(a0, b0, acc, 0, 0, 0);
        acc = __builtin_amdgcn_mfma_f32_16x16x32_bf16(a1, b1, acc, 0, 0, 0);
        // D: col = h, row = quad*4 + reg = m offset
        ushort4 o;
        o.x = f2bf(acc[0]); o.y = f2bf(acc[1]); o.z = f2bf(acc[2]); o.w = f2bf(acc[3]);
        *(ushort4*)(bias_ws + ((size_t)(b * 16 + col) * 512 + n) * 512 + m0 + quad * 4) = o;
    }
}

// ---------------------------------------------------------------------------
// K3: scores + masks + softmax -> attn fp32 (mandatory output), then fused
// P@V via MFMA reading back the L2-hot attn tile this block just wrote.
// grid 1024 = (b*h)*16 n-tiles of 32 rows; block 256.
// Phase 1: thread owns keys m=tid, tid+256. 2 barriers/row (wred parity-dbuf).
// Phase 2: wave (t = wid&1, kh = wid>>1): rows t*16..+16, K-half kh; LDS-reduce.
// ---------------------------------------------------------------------------
__global__ __launch_bounds__(256) void attn_av_kernel(
    const float* __restrict__ q_ws, const float* __restrict__ k_ws,
    const ushort* __restrict__ bias_ws, const ushort* __restrict__ vT,
    const int* __restrict__ am, float* __restrict__ attn,
    float* __restrict__ out_ws)
{
    __shared__ float qs[32 * 32];
    __shared__ int amq[32];
    __shared__ float wred[2][2][4];      // [row parity][max/sum][wave]
    __shared__ float red[4 * 528];       // phase-2 partials, 16x32 padded to 33
    const int tid = threadIdx.x, lane = tid & 63, wid = tid >> 6;
    const int bh = blockIdx.x >> 4, nt = blockIdx.x & 15;
    const int b = bh >> 4, h = bh & 15;
    const int n0 = nt * 32;

    {
        const float4* qg = (const float4*)(q_ws + (size_t)(bh * 512 + n0) * 32);
        ((float4*)qs)[tid] = qg[tid];          // 256 float4 = 32x32 fp32
    }
    if (tid < 32) amq[tid] = am[b * 512 + n0 + tid];

    float k0[32], k1[32];
    {
        const float4* kp  = (const float4*)(k_ws + (size_t)(bh * 512 + tid) * 32);
        const float4* kp2 = (const float4*)(k_ws + (size_t)(bh * 512 + tid + 256) * 32);
        #pragma unroll
        for (int j = 0; j < 8; ++j) {
            float4 u = kp[j];
            k0[j * 4 + 0] = u.x; k0[j * 4 + 1] = u.y; k0[j * 4 + 2] = u.z; k0[j * 4 + 3] = u.w;
            float4 u2 = kp2[j];
            k1[j * 4 + 0] = u2.x; k1[j * 4 + 1] = u2.y; k1[j * 4 + 2] = u2.z; k1[j * 4 + 3] = u2.w;
        }
    }
    const int km0 = am[b * 512 + tid];
    const int km1 = am[b * 512 + 256 + tid];
    __syncthreads();

    const float scale = 0.17677669529663687f;   // 1/sqrt(32)
    float* arow = attn + (size_t)(bh * 512 + n0) * 512;
    const ushort* brow = bias_ws + (size_t)(bh * 512 + n0) * 512;

    for (int r = 0; r < 32; ++r) {
        float s0 = 0.f, s1 = 0.f;
        const float4* q4 = (const float4*)(qs + r * 32);
        #pragma unroll
        for (int j = 0; j < 8; ++j) {
            float4 qv = q4[j];
            s0 = fmaf(qv.x, k0[j * 4 + 0], s0); s1 = fmaf(qv.x, k1[j * 4 + 0], s1);
            s0 = fmaf(qv.y, k0[j * 4 + 1], s0); s1 = fmaf(qv.y, k1[j * 4 + 1], s1);
            s0 = fmaf(qv.z, k0[j * 4 + 2], s0); s1 = fmaf(qv.z, k1[j * 4 + 2], s1);
            s0 = fmaf(qv.w, k0[j * 4 + 3], s0); s1 = fmaf(qv.w, k1[j * 4 + 3], s1);
        }
        float bias0 = bf2f(brow[r * 512 + tid]);
        float bias1 = bf2f(brow[r * 512 + tid + 256]);
        int rm = amq[r];
        s0 = s0 * scale + ((rm && km0) ? bias0 : 0.f);
        s1 = s1 * scale + ((rm && km1) ? bias1 : 0.f);
        if (!km0) s0 = -1e6f;
        if (!km1) s1 = -1e6f;

        const int par = r & 1;
        float mloc = fmaxf(s0, s1);
        #pragma unroll
        for (int off = 32; off > 0; off >>= 1) mloc = fmaxf(mloc, __shfl_xor(mloc, off));
        if (lane == 0) wred[par][0][wid] = mloc;
        __syncthreads();
        float mx = fmaxf(fmaxf(wred[par][0][0], wred[par][0][1]),
                         fmaxf(wred[par][0][2], wred[par][0][3]));
        float p0 = __expf(s0 - mx), p1 = __expf(s1 - mx);
        float sl = p0 + p1;
        #pragma unroll
        for (int off = 32; off > 0; off >>= 1) sl += __shfl_xor(sl, off);
        if (lane == 0) wred[par][1][wid] = sl;
        __syncthreads();
        float inv = 1.0f / (wred[par][1][0] + wred[par][1][1] +
                            wred[par][1][2] + wred[par][1][3]);
        arow[r * 512 + tid]       = p0 * inv;
        arow[r * 512 + tid + 256] = p1 * inv;
    }

    // ---- Phase 2: out[32 x 32dh] = P(32x512) @ V(512x32), K-split over waves
    __syncthreads();   // drains vmcnt -> attn stores visible via L2
    const int col = lane & 15, quad = lane >> 4;
    const int t = wid & 1, kh = wid >> 1;

    const float*  ap  = attn + (size_t)(bh * 512 + n0 + t * 16 + col) * 512 + kh * 256 + quad * 8;
    const ushort* vp0 = vT + (size_t)(bh * 32 + col) * 512 + kh * 256 + quad * 8;
    const ushort* vp1 = vp0 + 16 * 512;

    f32x4 acc0 = {0.f, 0.f, 0.f, 0.f}, acc1 = {0.f, 0.f, 0.f, 0.f};
    #pragma unroll
    for (int kc = 0; kc < 8; ++kc) {
        int mo = kc * 32;
        short8 a  = cvt8(*(const float4*)(ap + mo), *(const float4*)(ap + mo + 4));
        short8 v0 = *(const short8*)(vp0 + mo);
        short8 v1 = *(const short8*)(vp1 + mo);
        acc0 = __builtin_amdgcn_mfma_f32_16x16x32_bf16(a, v0, acc0, 0, 0, 0);
        acc1 = __builtin_amdgcn_mfma_f32_16x16x32_bf16(a, v1, acc1, 0, 0, 0);
    }
    {
        float* my = red + wid * 528;
        #pragma unroll
        for (int r = 0; r < 4; ++r) {
            my[(quad * 4 + r) * 33 + col]      = acc0[r];
            my[(quad * 4 + r) * 33 + 16 + col] = acc1[r];
        }
    }
    __syncthreads();
    if (wid < 2) {
        const float* r0 = red + wid * 528;         // (t=wid, kh=0)
        const float* r1 = red + (2 + wid) * 528;   // (t=wid, kh=1)
        float* op = out_ws + (size_t)(b * 512 + n0 + wid * 16 + quad * 4) * 512 + h * 32;
        #pragma unroll
        for (int r = 0; r < 4; ++r) {
            int i0 = (quad * 4 + r) * 33 + col;
            op[r * 512 + col]      = r0[i0] + r1[i0];
            op[r * 512 + 16 + col] = r0[i0 + 16] + r1[i0 + 16];
        }
    }
}

// ---------------------------------------------------------------------------
// K4: final = (out @ Wo) * row_mask -> fp32. grid 256 x 256; 8-row tiles.
// ---------------------------------------------------------------------------
__global__ __launch_bounds__(256) void out_kernel(
    const float* __restrict__ out_in, const float* __restrict__ Wo,
    const int* __restrict__ am, float* __restrict__ fin)
{
    __shared__ float xs[8 * 512];
    const int tid = threadIdx.x;
    const int row0 = blockIdx.x * 8;
    {
        const float4* g = (const float4*)(out_in + (size_t)row0 * 512);
        float4* s = (float4*)xs;
        #pragma unroll
        for (int i = 0; i < 4; ++i) s[tid + i * 256] = g[tid + i * 256];
    }
    __syncthreads();

    const int c0 = tid * 2;
    float acc[8][2];
    #pragma unroll
    for (int r = 0; r < 8; ++r) { acc[r][0] = 0.f; acc[r][1] = 0.f; }

    for (int kk = 0; kk < 512; kk += 4) {
        float w[4][2];
        #pragma unroll
        for (int j = 0; j < 4; ++j) {
            const float2 u = *(const float2*)(Wo + (kk + j) * 512 + c0);
            w[j][0] = u.x; w[j][1] = u.y;
        }
        #pragma unroll
        for (int r = 0; r < 8; ++r) {
            const float4 xv = *(const float4*)(xs + r * 512 + kk);
            acc[r][0] = fmaf(xv.x, w[0][0], acc[r][0]);
            acc[r][1] = fmaf(xv.x, w[0][1], acc[r][1]);
            acc[r][0] = fmaf(xv.y, w[1][0], acc[r][0]);
            acc[r][1] = fmaf(xv.y, w[1][1], acc[r][1]);
            acc[r][0] = fmaf(xv.z, w[2][0], acc[r][0]);
            acc[r][1] = fmaf(xv.z, w[2][1], acc[r][1]);
            acc[r][0] = fmaf(xv.w, w[3][0], acc[r][0]);
            acc[r][1] = fmaf(xv.w, w[3][1], acc[r][1]);
        }
    }
    #pragma unroll
    for (int r = 0; r < 8; ++r) {
        int row = row0 + r, b = row >> 9, n = row & 511;
        float msk = am[b * 512 + n] ? 1.0f : 0.0f;
        *(float2*)(fin + (size_t)row * 512 + c0) =
            make_float2(acc[r][0] * msk, acc[r][1] * msk);
    }
}

extern "C" void kernel_launch(void* const* d_in, const int* in_sizes, int n_in,
                              void* d_out, int out_size, void* d_ws, size_t ws_size,
                              hipStream_t stream)
{
    const float* x  = (const float*)d_in[0];
    const float* pb = (const float*)d_in[1];
    const float* Wq = (const float*)d_in[2];
    const float* Wk = (const float*)d_in[3];
    const float* Wv = (const float*)d_in[4];
    const float* Wo = (const float*)d_in[5];
    const float* Wp = (const float*)d_in[6];
    const int*   am = (const int*)d_in[7];

    float* fin  = (float*)d_out;
    float* attn = fin + (size_t)NB * NN * ND;      // 1,048,576 floats in

    float*  q_ws    = (float*)d_ws;                                  // 4 MB
    float*  k_ws    = (float*)((char*)d_ws + 4u * 1024 * 1024);      // 4 MB
    ushort* vT      = (ushort*)((char*)d_ws + 8u * 1024 * 1024);     // 2 MB
    float*  out_ws  = (float*)((char*)d_ws + 10u * 1024 * 1024);     // 4 MB
    ushort* bias_ws = (ushort*)((char*)d_ws + 14u * 1024 * 1024);    // 32 MB

    hipLaunchKernelGGL(qkv_kernel, dim3(256, 3), dim3(256), 0, stream,
                       x, Wq, Wk, Wv, q_ws, k_ws, vT);
    hipLaunchKernelGGL(bias_kernel, dim3(2048), dim3(256), 0, stream,
                       pb, Wp, bias_ws);
    hipLaunchKernelGGL(attn_av_kernel, dim3(1024), dim3(256), 0, stream,
                       q_ws, k_ws, bias_ws, vT, am, attn, out_ws);
    hipLaunchKernelGGL(out_kernel, dim3(256), dim3(256), 0, stream,
                       out_ws, Wo, am, fin);
}